// Round 2
// baseline (476.334 us; speedup 1.0000x reference)
//
#include <hip/hip_runtime.h>
#include <hip/hip_bf16.h>
#include <stdint.h>

// ---------------------------------------------------------------------------
// Problem constants
// ---------------------------------------------------------------------------
#define NCLS   6
#define NATOMS 5
#define B_     64
#define P_     196
#define D_     768
#define H_     3072
#define SEQ    (NCLS + P_)        // 202
#define NPATCH (B_ * P_)          // 12544
#define NPAIR  (B_ * NCLS)        // 384

typedef unsigned short ushort_t;
typedef __attribute__((ext_vector_type(8))) short  bf16x8;
typedef __attribute__((ext_vector_type(4))) float  f32x4;

// ---------------------------------------------------------------------------
// Helpers
// ---------------------------------------------------------------------------
// fast tanh-form GELU: x * e / (e + 1),  e = exp(2*(0.79788456*x + 0.035677408*x^3))
// max abs error vs exact-erf GELU ~1e-3 (threshold budget 3.98e-2)
__device__ __forceinline__ float gelu_fast(float x) {
    float x2 = x * x;
    float y  = x * (1.59576912f + 0.07135482f * x2);  // 2*(c0 + c1*x^2)*x
    float e  = __expf(y);
    return x * e / (e + 1.0f);
}

// fp32 -> bf16 (round to nearest even), raw bits
__device__ __forceinline__ ushort_t f2bf(float f) {
    uint32_t u = __builtin_bit_cast(uint32_t, f);
    u = (u + 0x7fffu + ((u >> 16) & 1u)) >> 16;
    return (ushort_t)u;
}

// async global -> LDS, 16 bytes per lane (wave-uniform base + lane*16 layout)
__device__ __forceinline__ void gload16(const ushort_t* g, ushort_t* l) {
    __builtin_amdgcn_global_load_lds(
        (const __attribute__((address_space(1))) uint32_t*)g,
        (__attribute__((address_space(3))) uint32_t*)l,
        16, 0, 0);
}

// ---------------------------------------------------------------------------
// fp32 -> bf16 conversion kernels
// ---------------------------------------------------------------------------
__global__ void cvt4_kernel(const float* __restrict__ in, ushort_t* __restrict__ out, int n) {
    int i = (blockIdx.x * blockDim.x + threadIdx.x) * 4;
    if (i >= n) return;
    float4 v = *(const float4*)(in + i);
    ushort4 o;
    o.x = f2bf(v.x); o.y = f2bf(v.y); o.z = f2bf(v.z); o.w = f2bf(v.w);
    *(ushort4*)(out + i) = o;
}

// split x (B, SEQ, D) fp32 into patch tokens (NPATCH, D) bf16 and cls tokens (NPAIR, D) bf16
__global__ void split_x_kernel(const float* __restrict__ x,
                               ushort_t* __restrict__ xp,
                               ushort_t* __restrict__ cls) {
    int i = (blockIdx.x * blockDim.x + threadIdx.x) * 4;
    const int total = B_ * SEQ * D_;
    if (i >= total) return;
    int row = i / D_;
    int col = i - row * D_;   // D_ % 4 == 0 so all 4 elems share a row
    int b = row / SEQ, s = row - b * SEQ;
    float4 v = *(const float4*)(x + i);
    ushort4 o;
    o.x = f2bf(v.x); o.y = f2bf(v.y); o.z = f2bf(v.z); o.w = f2bf(v.w);
    if (s < NCLS) {
        *(ushort4*)(cls + (size_t)(b * NCLS + s) * D_ + col) = o;
    } else {
        *(ushort4*)(xp + (size_t)(b * P_ + (s - NCLS)) * D_ + col) = o;
    }
}

// ---------------------------------------------------------------------------
// Gate: logits, weight, src/dst atom per (b, n) pair. One wave per pair.
// ---------------------------------------------------------------------------
__global__ void gate_kernel(const float* __restrict__ x, const float* __restrict__ gd,
                            int* __restrict__ src, int* __restrict__ dst,
                            float* __restrict__ wgt) {
    int r = blockIdx.x;           // pair index 0..383
    int b = r / NCLS, n = r - b * NCLS;
    const float* xr = x + (size_t)(b * SEQ + n) * D_;
    const float* g  = gd + (size_t)n * D_;
    int lane = threadIdx.x;
    float s = 0.f;
    for (int k = lane; k < D_; k += 64) s += xr[k] * g[k];
    #pragma unroll
    for (int off = 32; off > 0; off >>= 1) s += __shfl_down(s, off, 64);
    if (lane == 0) {
        float logit = s;
        bool left = (logit >= 0.f);
        float p = 1.f / (1.f + expf(-logit));
        float w = left ? p : (1.f - p);
        const int LK[NCLS] = {3, 4, 8, 9, 13, 14};
        const int RK[NCLS] = {15, 20, 16, 21, 17, 22};
        int key = left ? LK[n] : RK[n];
        src[r] = key / NATOMS;
        dst[r] = key % NATOMS;
        wgt[r] = w;
    }
}

// ---------------------------------------------------------------------------
// 2-phase double-buffered GEMM:  C[m,n] = sum_k A[m,k] * B[n,k]  (B is N x K)
// 128x128 tile, BK=64, 4 waves (2x2), 16x16x32 bf16 MFMA, global_load_lds,
// STAGE(t+1) issued BEFORE compute(t); one vmcnt(0)+barrier per K-tile.
// MODE 0: H1 = bf16(gelu(acc + bias[n]))                       (patch layer 1)
// MODE 1: out[(b*SEQ+NCLS+p)*D_+n] = acc + bias[n]             (patch layer 2)
// MODE 2: if src[m]==atom: HID = bf16(gelu(acc + bias[atom*H_+n]))  (cls in)
// MODE 3: if dst[m]==atom: out[(b*SEQ+nn)*D_+n] = (acc + bias[atom*D_+n])*wgt[m]
// ---------------------------------------------------------------------------
template <int MODE>
__global__ __launch_bounds__(256)
void gemm2p(const ushort_t* __restrict__ A,
            const ushort_t* __restrict__ Bm,
            int N, int K,
            const float* __restrict__ bias,
            float* __restrict__ outF,
            ushort_t* __restrict__ outB,
            const int* __restrict__ selIdx,
            const float* __restrict__ wgt) {
    const int tile_m = blockIdx.x;
    const int tile_n = blockIdx.y;
    const int atom   = blockIdx.z;

    const ushort_t* Ab = A  + (size_t)tile_m * 128 * K;
    const ushort_t* Bb = Bm + ((size_t)atom * N + (size_t)tile_n * 128) * K;

    __shared__ __align__(16) ushort_t sA[2][128 * 64];   // 2 x 16 KB
    __shared__ __align__(16) ushort_t sB[2][128 * 64];   // 2 x 16 KB

    const int tid  = threadIdx.x;
    const int lane = tid & 63;
    const int wave = tid >> 6;
    const int wr = wave >> 1;     // wave row (0..1), 64 rows each
    const int wc = wave & 1;      // wave col (0..1), 64 cols each

    f32x4 acc[4][4];
    #pragma unroll
    for (int i = 0; i < 4; i++)
        #pragma unroll
        for (int j = 0; j < 4; j++)
            acc[i][j] = (f32x4){0.f, 0.f, 0.f, 0.f};

    // staging map: thread t, load l -> LDS elem (l*256+t)*8 -> row l*32+t/8, col (t%8)*8
    const int srow = tid >> 3;          // 0..31
    const int scol = (tid & 7) * 8;     // 0..56
    const int nkt  = K >> 6;            // K-tiles of 64

    const int frow = lane & 15;
    const int fcol = (lane >> 4) * 8;

    // ---- prologue: stage tile 0 into buf 0
    {
        const ushort_t* ga = Ab + (size_t)srow * K + scol;
        const ushort_t* gb = Bb + (size_t)srow * K + scol;
        #pragma unroll
        for (int l = 0; l < 4; l++) {
            gload16(ga + (size_t)l * 32 * K, &sA[0][(size_t)tid * 8 + l * 2048]);
            gload16(gb + (size_t)l * 32 * K, &sB[0][(size_t)tid * 8 + l * 2048]);
        }
    }
    asm volatile("s_waitcnt vmcnt(0)" ::: "memory");
    __syncthreads();

    int cur = 0;
    for (int t = 0; t + 1 < nkt; ++t) {
        // ---- issue next K-tile's staging loads (into the other buffer)
        {
            const int kt = t + 1;
            const ushort_t* ga = Ab + (size_t)srow * K + (size_t)kt * 64 + scol;
            const ushort_t* gb = Bb + (size_t)srow * K + (size_t)kt * 64 + scol;
            const int nb = cur ^ 1;
            #pragma unroll
            for (int l = 0; l < 4; l++) {
                gload16(ga + (size_t)l * 32 * K, &sA[nb][(size_t)tid * 8 + l * 2048]);
                gload16(gb + (size_t)l * 32 * K, &sB[nb][(size_t)tid * 8 + l * 2048]);
            }
        }
        // ---- compute current tile (loads overlap with this)
        {
            bf16x8 af[2][4], bfr[2][4];
            #pragma unroll
            for (int ks = 0; ks < 2; ks++)
                #pragma unroll
                for (int i = 0; i < 4; i++) {
                    af[ks][i]  = *(const bf16x8*)(&sA[cur][(wr * 64 + i * 16 + frow) * 64 + ks * 32 + fcol]);
                    bfr[ks][i] = *(const bf16x8*)(&sB[cur][(wc * 64 + i * 16 + frow) * 64 + ks * 32 + fcol]);
                }
            #pragma unroll
            for (int ks = 0; ks < 2; ks++)
                #pragma unroll
                for (int mi = 0; mi < 4; mi++)
                    #pragma unroll
                    for (int ni = 0; ni < 4; ni++)
                        acc[mi][ni] = __builtin_amdgcn_mfma_f32_16x16x32_bf16(
                            af[ks][mi], bfr[ks][ni], acc[mi][ni], 0, 0, 0);
        }
        // ---- drain this iteration's staging, flip
        asm volatile("s_waitcnt vmcnt(0)" ::: "memory");
        __syncthreads();
        cur ^= 1;
    }
    // ---- last tile (no prefetch)
    {
        bf16x8 af[2][4], bfr[2][4];
        #pragma unroll
        for (int ks = 0; ks < 2; ks++)
            #pragma unroll
            for (int i = 0; i < 4; i++) {
                af[ks][i]  = *(const bf16x8*)(&sA[cur][(wr * 64 + i * 16 + frow) * 64 + ks * 32 + fcol]);
                bfr[ks][i] = *(const bf16x8*)(&sB[cur][(wc * 64 + i * 16 + frow) * 64 + ks * 32 + fcol]);
            }
        #pragma unroll
        for (int ks = 0; ks < 2; ks++)
            #pragma unroll
            for (int mi = 0; mi < 4; mi++)
                #pragma unroll
                for (int ni = 0; ni < 4; ni++)
                    acc[mi][ni] = __builtin_amdgcn_mfma_f32_16x16x32_bf16(
                        af[ks][mi], bfr[ks][ni], acc[mi][ni], 0, 0, 0);
    }

    // ---- epilogue: C/D layout col = lane&15, row = (lane>>4)*4 + reg
    const int fq = lane >> 4;
    #pragma unroll
    for (int mi = 0; mi < 4; mi++) {
        #pragma unroll
        for (int ni = 0; ni < 4; ni++) {
            int n = tile_n * 128 + wc * 64 + ni * 16 + frow;
            float bn;
            if constexpr (MODE == 2)      bn = bias[atom * H_ + n];
            else if constexpr (MODE == 3) bn = bias[atom * D_ + n];
            else                          bn = bias[n];
            #pragma unroll
            for (int r = 0; r < 4; r++) {
                int m = tile_m * 128 + wr * 64 + mi * 16 + fq * 4 + r;
                float v = acc[mi][ni][r];
                if constexpr (MODE == 0) {
                    outB[(size_t)m * N + n] = f2bf(gelu_fast(v + bn));
                } else if constexpr (MODE == 1) {
                    int b = m / P_, p = m - b * P_;
                    outF[(size_t)(b * SEQ + NCLS + p) * D_ + n] = v + bn;
                } else if constexpr (MODE == 2) {
                    if (selIdx[m] == atom)
                        outB[(size_t)m * N + n] = f2bf(gelu_fast(v + bn));
                } else { // MODE 3
                    if (selIdx[m] == atom) {
                        int b = m / NCLS, nn = m - b * NCLS;
                        outF[(size_t)(b * SEQ + nn) * D_ + n] = (v + bn) * wgt[m];
                    }
                }
            }
        }
    }
}

// ---------------------------------------------------------------------------
// Launch
// ---------------------------------------------------------------------------
extern "C" void kernel_launch(void* const* d_in, const int* in_sizes, int n_in,
                              void* d_out, int out_size, void* d_ws, size_t ws_size,
                              hipStream_t stream) {
    const float* x   = (const float*)d_in[0];
    const float* w1  = (const float*)d_in[1];
    const float* b1  = (const float*)d_in[2];
    const float* w2  = (const float*)d_in[3];
    const float* b2  = (const float*)d_in[4];
    const float* gd  = (const float*)d_in[5];
    const float* aiw = (const float*)d_in[6];
    const float* aib = (const float*)d_in[7];
    const float* aow = (const float*)d_in[8];
    const float* aob = (const float*)d_in[9];
    float* out = (float*)d_out;

    // workspace layout (all 16B aligned; total ~149 MiB)
    char* ws = (char*)d_ws;
    ushort_t* Xp   = (ushort_t*)ws; ws += (size_t)NPATCH * D_ * 2;
    ushort_t* W1b  = (ushort_t*)ws; ws += (size_t)H_ * D_ * 2;
    ushort_t* W2b  = (ushort_t*)ws; ws += (size_t)D_ * H_ * 2;
    ushort_t* H1   = (ushort_t*)ws; ws += (size_t)NPATCH * H_ * 2;
    ushort_t* CLSb = (ushort_t*)ws; ws += (size_t)NPAIR * D_ * 2;
    ushort_t* AIWb = (ushort_t*)ws; ws += (size_t)NATOMS * H_ * D_ * 2;
    ushort_t* AOWb = (ushort_t*)ws; ws += (size_t)NATOMS * D_ * H_ * 2;
    ushort_t* HID  = (ushort_t*)ws; ws += (size_t)NPAIR * H_ * 2;
    int*   SRC = (int*)ws;   ws += NPAIR * 4;
    int*   DST = (int*)ws;   ws += NPAIR * 4;
    float* WGT = (float*)ws; ws += NPAIR * 4;

    // conversions
    split_x_kernel<<<(B_ * SEQ * D_ / 4 + 255) / 256, 256, 0, stream>>>(x, Xp, CLSb);
    cvt4_kernel<<<(H_ * D_ / 4 + 255) / 256, 256, 0, stream>>>(w1, W1b, H_ * D_);
    cvt4_kernel<<<(D_ * H_ / 4 + 255) / 256, 256, 0, stream>>>(w2, W2b, D_ * H_);
    cvt4_kernel<<<(NATOMS * H_ * D_ / 4 + 255) / 256, 256, 0, stream>>>(aiw, AIWb, NATOMS * H_ * D_);
    cvt4_kernel<<<(NATOMS * D_ * H_ / 4 + 255) / 256, 256, 0, stream>>>(aow, AOWb, NATOMS * D_ * H_);
    gate_kernel<<<NPAIR, 64, 0, stream>>>(x, gd, SRC, DST, WGT);

    // patch MLP: (12544x768)@(3072x768)^T -> gelu -> (12544x3072)@(768x3072)^T
    gemm2p<0><<<dim3(NPATCH / 128, H_ / 128, 1), 256, 0, stream>>>(
        Xp, W1b, H_, D_, b1, nullptr, H1, nullptr, nullptr);
    gemm2p<1><<<dim3(NPATCH / 128, D_ / 128, 1), 256, 0, stream>>>(
        H1, W2b, D_, H_, b2, out, nullptr, nullptr, nullptr);

    // cls path: dense all-atom GEMMs with masked epilogue scatter
    gemm2p<2><<<dim3(NPAIR / 128, H_ / 128, NATOMS), 256, 0, stream>>>(
        CLSb, AIWb, H_, D_, aib, nullptr, HID, SRC, nullptr);
    gemm2p<3><<<dim3(NPAIR / 128, D_ / 128, NATOMS), 256, 0, stream>>>(
        HID, AOWb, D_, H_, aob, out, nullptr, DST, WGT);
}

// Round 3
// 339.920 us; speedup vs baseline: 1.4013x; 1.4013x over previous
//
#include <hip/hip_runtime.h>
#include <hip/hip_bf16.h>
#include <stdint.h>

// ---------------------------------------------------------------------------
// Problem constants
// ---------------------------------------------------------------------------
#define NCLS   6
#define NATOMS 5
#define B_     64
#define P_     196
#define D_     768
#define H_     3072
#define SEQ    (NCLS + P_)        // 202
#define NPATCH (B_ * P_)          // 12544
#define NPAIR  (B_ * NCLS)        // 384

typedef unsigned short ushort_t;
typedef __attribute__((ext_vector_type(8))) short  bf16x8;
typedef __attribute__((ext_vector_type(4))) float  f32x4;

// ---------------------------------------------------------------------------
// Helpers
// ---------------------------------------------------------------------------
// fast tanh-form GELU (max abs err ~1e-3; threshold budget 3.98e-2)
__device__ __forceinline__ float gelu_fast(float x) {
    float x2 = x * x;
    float y  = x * (1.59576912f + 0.07135482f * x2);
    float e  = __expf(y);
    return x * e / (e + 1.0f);
}

__device__ __forceinline__ ushort_t f2bf(float f) {
    uint32_t u = __builtin_bit_cast(uint32_t, f);
    u = (u + 0x7fffu + ((u >> 16) & 1u)) >> 16;
    return (ushort_t)u;
}

__device__ __forceinline__ void gload16(const ushort_t* g, ushort_t* l) {
    __builtin_amdgcn_global_load_lds(
        (const __attribute__((address_space(1))) uint32_t*)g,
        (__attribute__((address_space(3))) uint32_t*)l,
        16, 0, 0);
}

// ---------------------------------------------------------------------------
// fp32 -> bf16 conversion kernels
// ---------------------------------------------------------------------------
__global__ void cvt4_kernel(const float* __restrict__ in, ushort_t* __restrict__ out, int n) {
    int i = (blockIdx.x * blockDim.x + threadIdx.x) * 4;
    if (i >= n) return;
    float4 v = *(const float4*)(in + i);
    ushort4 o;
    o.x = f2bf(v.x); o.y = f2bf(v.y); o.z = f2bf(v.z); o.w = f2bf(v.w);
    *(ushort4*)(out + i) = o;
}

__global__ void split_x_kernel(const float* __restrict__ x,
                               ushort_t* __restrict__ xp,
                               ushort_t* __restrict__ cls) {
    int i = (blockIdx.x * blockDim.x + threadIdx.x) * 4;
    const int total = B_ * SEQ * D_;
    if (i >= total) return;
    int row = i / D_;
    int col = i - row * D_;
    int b = row / SEQ, s = row - b * SEQ;
    float4 v = *(const float4*)(x + i);
    ushort4 o;
    o.x = f2bf(v.x); o.y = f2bf(v.y); o.z = f2bf(v.z); o.w = f2bf(v.w);
    if (s < NCLS) {
        *(ushort4*)(cls + (size_t)(b * NCLS + s) * D_ + col) = o;
    } else {
        *(ushort4*)(xp + (size_t)(b * P_ + (s - NCLS)) * D_ + col) = o;
    }
}

// ---------------------------------------------------------------------------
// Gate
// ---------------------------------------------------------------------------
__global__ void gate_kernel(const float* __restrict__ x, const float* __restrict__ gd,
                            int* __restrict__ src, int* __restrict__ dst,
                            float* __restrict__ wgt) {
    int r = blockIdx.x;
    int b = r / NCLS, n = r - b * NCLS;
    const float* xr = x + (size_t)(b * SEQ + n) * D_;
    const float* g  = gd + (size_t)n * D_;
    int lane = threadIdx.x;
    float s = 0.f;
    for (int k = lane; k < D_; k += 64) s += xr[k] * g[k];
    #pragma unroll
    for (int off = 32; off > 0; off >>= 1) s += __shfl_down(s, off, 64);
    if (lane == 0) {
        float logit = s;
        bool left = (logit >= 0.f);
        float p = 1.f / (1.f + expf(-logit));
        float w = left ? p : (1.f - p);
        const int LK[NCLS] = {3, 4, 8, 9, 13, 14};
        const int RK[NCLS] = {15, 20, 16, 21, 17, 22};
        int key = left ? LK[n] : RK[n];
        src[r] = key / NATOMS;
        dst[r] = key % NATOMS;
        wgt[r] = w;
    }
}

// ---------------------------------------------------------------------------
// 2-phase GEMM building blocks (BK = 64 fixed)
// ---------------------------------------------------------------------------
// stage a ROWS x 64 bf16 tile: chunk c = l*NT+tid -> LDS elems [c*8, c*8+8)
// = row c/8, col (c&7)*8.  LDS dest is linear (wave-uniform base + lane*16).
template <int ROWS, int NT>
__device__ __forceinline__ void stage64(const ushort_t* __restrict__ gbase, int K,
                                        int k0, ushort_t* lds, int tid) {
    constexpr int LOADS = ROWS * 64 * 2 / (NT * 16);
    #pragma unroll
    for (int l = 0; l < LOADS; ++l) {
        int c = l * NT + tid;
        gload16(gbase + (size_t)(c >> 3) * K + k0 + ((c & 7) << 3),
                lds + (size_t)c * 8);
    }
}

template <int FM, int FN>
__device__ __forceinline__ void compute64(const ushort_t* sA, const ushort_t* sB,
                                          int arow0, int brow0, int lane,
                                          f32x4 (&acc)[FM][FN]) {
    const int frow = lane & 15;
    const int fcol = (lane >> 4) * 8;
    #pragma unroll
    for (int ks = 0; ks < 2; ++ks) {
        bf16x8 af[FM], bf[FN];
        #pragma unroll
        for (int mi = 0; mi < FM; ++mi)
            af[mi] = *(const bf16x8*)(sA + (size_t)(arow0 + mi * 16 + frow) * 64 + ks * 32 + fcol);
        #pragma unroll
        for (int ni = 0; ni < FN; ++ni)
            bf[ni] = *(const bf16x8*)(sB + (size_t)(brow0 + ni * 16 + frow) * 64 + ks * 32 + fcol);
        #pragma unroll
        for (int mi = 0; mi < FM; ++mi)
            #pragma unroll
            for (int ni = 0; ni < FN; ++ni)
                acc[mi][ni] = __builtin_amdgcn_mfma_f32_16x16x32_bf16(
                    af[mi], bf[ni], acc[mi][ni], 0, 0, 0);
    }
}

// ---------------------------------------------------------------------------
// 2-phase double-buffered GEMM, DISTINCT static LDS buffers (A0/A1/B0/B1) so
// the compiler can prove stage(next) doesn't alias compute(cur) and overlap.
// 1-D grid (x), bijective XCD-chunk swizzle, tile_n fastest (A-panel reuse
// within an XCD chunk). K-tile count must be even (true for K=768,3072).
// ---------------------------------------------------------------------------
template <int MODE, int BM, int BN, int WM, int WN>
__global__ __launch_bounds__(WM * WN * 64, 2)
void gemm2p(const ushort_t* __restrict__ A,
            const ushort_t* __restrict__ Bm,
            int N, int K, int grid_n,
            const float* __restrict__ bias,
            float* __restrict__ outF,
            ushort_t* __restrict__ outB,
            const int* __restrict__ selIdx,
            const float* __restrict__ wgt) {
    constexpr int NT = WM * WN * 64;
    constexpr int FM = BM / WM / 16;
    constexpr int FN = BN / WN / 16;

    __shared__ __align__(16) ushort_t A0[BM * 64], A1[BM * 64];
    __shared__ __align__(16) ushort_t B0[BN * 64], B1[BN * 64];

    // bijective XCD-chunk swizzle (m204 formula), tile_n fastest
    const int nwg = gridDim.x;
    int bid = blockIdx.x;
    int q = nwg >> 3, r = nwg & 7;
    int xcd = bid & 7, slot = bid >> 3;
    int wg = (xcd < r ? xcd * (q + 1) : r * (q + 1) + (xcd - r) * q) + slot;
    int tile_m = wg / grid_n;
    int tile_n = wg - tile_m * grid_n;
    const int atom = blockIdx.z;

    const ushort_t* Ab = A  + (size_t)tile_m * BM * K;
    const ushort_t* Bb = Bm + ((size_t)atom * N + (size_t)tile_n * BN) * K;

    const int tid  = threadIdx.x;
    const int lane = tid & 63;
    const int wave = tid >> 6;
    const int arow0 = (wave / WN) * (BM / WM);
    const int brow0 = (wave % WN) * (BN / WN);

    f32x4 acc[FM][FN];
    #pragma unroll
    for (int i = 0; i < FM; i++)
        #pragma unroll
        for (int j = 0; j < FN; j++)
            acc[i][j] = (f32x4){0.f, 0.f, 0.f, 0.f};

    const int nkt = K >> 6;   // even for all our K

    stage64<BM, NT>(Ab, K, 0, A0, tid);
    stage64<BN, NT>(Bb, K, 0, B0, tid);
    asm volatile("s_waitcnt vmcnt(0)" ::: "memory");
    __syncthreads();

    for (int t = 0; t < nkt; t += 2) {
        // stage odd tile into buf1 while computing buf0
        stage64<BM, NT>(Ab, K, (t + 1) << 6, A1, tid);
        stage64<BN, NT>(Bb, K, (t + 1) << 6, B1, tid);
        compute64<FM, FN>(A0, B0, arow0, brow0, lane, acc);
        asm volatile("s_waitcnt vmcnt(0)" ::: "memory");
        __syncthreads();
        // stage next even tile into buf0 while computing buf1
        if (t + 2 < nkt) {
            stage64<BM, NT>(Ab, K, (t + 2) << 6, A0, tid);
            stage64<BN, NT>(Bb, K, (t + 2) << 6, B0, tid);
        }
        compute64<FM, FN>(A1, B1, arow0, brow0, lane, acc);
        asm volatile("s_waitcnt vmcnt(0)" ::: "memory");
        __syncthreads();
    }

    // epilogue: C/D layout col = lane&15, row = (lane>>4)*4 + reg
    const int frow = lane & 15;
    const int fq   = lane >> 4;
    #pragma unroll
    for (int mi = 0; mi < FM; mi++) {
        #pragma unroll
        for (int ni = 0; ni < FN; ni++) {
            int n = tile_n * BN + brow0 + ni * 16 + frow;
            float bn;
            if constexpr (MODE == 2)      bn = bias[atom * H_ + n];
            else if constexpr (MODE == 3) bn = bias[atom * D_ + n];
            else                          bn = bias[n];
            #pragma unroll
            for (int rr = 0; rr < 4; rr++) {
                int m = tile_m * BM + arow0 + mi * 16 + fq * 4 + rr;
                float v = acc[mi][ni][rr];
                if constexpr (MODE == 0) {
                    outB[(size_t)m * N + n] = f2bf(gelu_fast(v + bn));
                } else if constexpr (MODE == 1) {
                    int b = m / P_, p = m - b * P_;
                    outF[(size_t)(b * SEQ + NCLS + p) * D_ + n] = v + bn;
                } else if constexpr (MODE == 2) {
                    if (selIdx[m] == atom)
                        outB[(size_t)m * N + n] = f2bf(gelu_fast(v + bn));
                } else { // MODE 3
                    if (selIdx[m] == atom) {
                        int b = m / NCLS, nn = m - b * NCLS;
                        outF[(size_t)(b * SEQ + nn) * D_ + n] = (v + bn) * wgt[m];
                    }
                }
            }
        }
    }
}

// ---------------------------------------------------------------------------
// Launch
// ---------------------------------------------------------------------------
extern "C" void kernel_launch(void* const* d_in, const int* in_sizes, int n_in,
                              void* d_out, int out_size, void* d_ws, size_t ws_size,
                              hipStream_t stream) {
    const float* x   = (const float*)d_in[0];
    const float* w1  = (const float*)d_in[1];
    const float* b1  = (const float*)d_in[2];
    const float* w2  = (const float*)d_in[3];
    const float* b2  = (const float*)d_in[4];
    const float* gd  = (const float*)d_in[5];
    const float* aiw = (const float*)d_in[6];
    const float* aib = (const float*)d_in[7];
    const float* aow = (const float*)d_in[8];
    const float* aob = (const float*)d_in[9];
    float* out = (float*)d_out;

    char* ws = (char*)d_ws;
    ushort_t* Xp   = (ushort_t*)ws; ws += (size_t)NPATCH * D_ * 2;
    ushort_t* W1b  = (ushort_t*)ws; ws += (size_t)H_ * D_ * 2;
    ushort_t* W2b  = (ushort_t*)ws; ws += (size_t)D_ * H_ * 2;
    ushort_t* H1   = (ushort_t*)ws; ws += (size_t)NPATCH * H_ * 2;
    ushort_t* CLSb = (ushort_t*)ws; ws += (size_t)NPAIR * D_ * 2;
    ushort_t* AIWb = (ushort_t*)ws; ws += (size_t)NATOMS * H_ * D_ * 2;
    ushort_t* AOWb = (ushort_t*)ws; ws += (size_t)NATOMS * D_ * H_ * 2;
    ushort_t* HID  = (ushort_t*)ws; ws += (size_t)NPAIR * H_ * 2;
    int*   SRC = (int*)ws;   ws += NPAIR * 4;
    int*   DST = (int*)ws;   ws += NPAIR * 4;
    float* WGT = (float*)ws; ws += NPAIR * 4;

    // conversions
    split_x_kernel<<<(B_ * SEQ * D_ / 4 + 255) / 256, 256, 0, stream>>>(x, Xp, CLSb);
    cvt4_kernel<<<(H_ * D_ / 4 + 255) / 256, 256, 0, stream>>>(w1, W1b, H_ * D_);
    cvt4_kernel<<<(D_ * H_ / 4 + 255) / 256, 256, 0, stream>>>(w2, W2b, D_ * H_);
    cvt4_kernel<<<(NATOMS * H_ * D_ / 4 + 255) / 256, 256, 0, stream>>>(aiw, AIWb, NATOMS * H_ * D_);
    cvt4_kernel<<<(NATOMS * D_ * H_ / 4 + 255) / 256, 256, 0, stream>>>(aow, AOWb, NATOMS * D_ * H_);
    gate_kernel<<<NPAIR, 64, 0, stream>>>(x, gd, SRC, DST, WGT);

    // patch MLP
    gemm2p<0, 128, 128, 2, 2><<<dim3(NPATCH / 128 * (H_ / 128), 1, 1), 256, 0, stream>>>(
        Xp, W1b, H_, D_, H_ / 128, b1, nullptr, H1, nullptr, nullptr);
    gemm2p<1, 128, 128, 2, 2><<<dim3(NPATCH / 128 * (D_ / 128), 1, 1), 256, 0, stream>>>(
        H1, W2b, D_, H_, D_ / 128, b2, out, nullptr, nullptr, nullptr);

    // cls path: dense all-atom GEMMs with masked epilogue scatter (64-row tiles)
    gemm2p<2, 64, 128, 1, 2><<<dim3(NPAIR / 64 * (H_ / 128), 1, NATOMS), 128, 0, stream>>>(
        CLSb, AIWb, H_, D_, H_ / 128, aib, nullptr, HID, SRC, nullptr);
    gemm2p<3, 64, 128, 1, 2><<<dim3(NPAIR / 64 * (D_ / 128), 1, NATOMS), 128, 0, stream>>>(
        HID, AOWb, D_, H_, D_ / 128, aob, out, nullptr, DST, WGT);
}